// Round 7
// baseline (173.592 us; speedup 1.0000x reference)
//
#include <hip/hip_runtime.h>
#include <math.h>

#define NB 64
#define NC 512
#define NT 1000
#define NH 512
#define TWOC 1024
#define NT4 250   // NT/4 float4 per row
#define TAIL 58   // 250 - 192
#define NWAVES 8192   // persistent waves for stats; 4 rows each

typedef float vfloat4 __attribute__((ext_vector_type(4)));

struct RowBuf {
    float4 a0, a1, a2, a3, b0, b1, b2, b3, c0, c1, c2, c3;
};

__device__ __forceinline__ void load_row(const float4* __restrict__ x0,
                                         const float4* __restrict__ x1,
                                         const float4* __restrict__ x2,
                                         int row, int lane, int i3, RowBuf& r) {
    const float4* p0 = x0 + (size_t)row * NT4;
    const float4* p1 = x1 + (size_t)row * NT4;
    const float4* p2 = x2 + (size_t)row * NT4;
    r.a0 = p0[lane]; r.a1 = p0[lane + 64]; r.a2 = p0[lane + 128]; r.a3 = p0[i3];
    r.b0 = p1[lane]; r.b1 = p1[lane + 64]; r.b2 = p1[lane + 128]; r.b3 = p1[i3];
    r.c0 = p2[lane]; r.c1 = p2[lane + 64]; r.c2 = p2[lane + 128]; r.c3 = p2[i3];
}

__device__ __forceinline__ void reduce_row(const RowBuf& r, float m3, int lane, int row,
                                           float* __restrict__ stats) {
    float s0 = 0.f, q0 = 0.f, s1 = 0.f, q1 = 0.f;
    float s2 = 0.f, q2 = 0.f, s3 = 0.f, q3 = 0.f;
    float v;
    v = r.a0.x + r.b0.x + r.c0.x; s0 += v; q0 += v * v;
    v = r.a0.y + r.b0.y + r.c0.y; s0 += v; q0 += v * v;
    v = r.a0.z + r.b0.z + r.c0.z; s0 += v; q0 += v * v;
    v = r.a0.w + r.b0.w + r.c0.w; s0 += v; q0 += v * v;
    v = r.a1.x + r.b1.x + r.c1.x; s1 += v; q1 += v * v;
    v = r.a1.y + r.b1.y + r.c1.y; s1 += v; q1 += v * v;
    v = r.a1.z + r.b1.z + r.c1.z; s1 += v; q1 += v * v;
    v = r.a1.w + r.b1.w + r.c1.w; s1 += v; q1 += v * v;
    v = r.a2.x + r.b2.x + r.c2.x; s2 += v; q2 += v * v;
    v = r.a2.y + r.b2.y + r.c2.y; s2 += v; q2 += v * v;
    v = r.a2.z + r.b2.z + r.c2.z; s2 += v; q2 += v * v;
    v = r.a2.w + r.b2.w + r.c2.w; s2 += v; q2 += v * v;
    v = (r.a3.x + r.b3.x + r.c3.x) * m3; s3 += v; q3 += v * v;
    v = (r.a3.y + r.b3.y + r.c3.y) * m3; s3 += v; q3 += v * v;
    v = (r.a3.z + r.b3.z + r.c3.z) * m3; s3 += v; q3 += v * v;
    v = (r.a3.w + r.b3.w + r.c3.w) * m3; s3 += v; q3 += v * v;

    float s  = (s0 + s1) + (s2 + s3);
    float sq = (q0 + q1) + (q2 + q3);
    #pragma unroll
    for (int off = 32; off; off >>= 1) {
        s  += __shfl_down(s,  off);
        sq += __shfl_down(sq, off);
    }
    if (lane == 0) {
        const float mean = s / (float)NT;
        const float var  = (sq - s * s / (float)NT) / (float)(NT - 1);
        const float sd   = sqrtf(fmaxf(var, 0.f));
        const int b = row >> 9;
        const int c = row & (NC - 1);
        stats[b * TWOC + c]      = mean;
        stats[b * TWOC + NC + c] = sd;
    }
}

// ---------------- Kernel 1: persistent waves, 4 rows/wave, 2-row pipeline ----------------
// While row k is reduced (dependent shuffle chain), row k+1's 12 loads are in
// flight and REQUIRED next iteration -> compiler cannot collapse the MLP.
__global__ __launch_bounds__(256) void stats_kernel(const float* __restrict__ x0f,
                                                    const float* __restrict__ x1f,
                                                    const float* __restrict__ x2f,
                                                    float* __restrict__ stats) {
    const int wid  = blockIdx.x * 4 + (threadIdx.x >> 6);   // 0..8191
    const int lane = threadIdx.x & 63;
    const bool tail = lane < TAIL;
    const int  i3   = tail ? (192 + lane) : lane;
    const float m3  = tail ? 1.f : 0.f;

    const float4* x0 = (const float4*)x0f;
    const float4* x1 = (const float4*)x1f;
    const float4* x2 = (const float4*)x2f;

    RowBuf X, Y;
    load_row(x0, x1, x2, wid, lane, i3, X);                     // row k=0
    __builtin_amdgcn_sched_barrier(0);
    load_row(x0, x1, x2, wid + NWAVES, lane, i3, Y);            // row k=1
    __builtin_amdgcn_sched_barrier(0);
    reduce_row(X, m3, lane, wid, stats);                        // consume k=0
    load_row(x0, x1, x2, wid + 2 * NWAVES, lane, i3, X);        // row k=2
    __builtin_amdgcn_sched_barrier(0);
    reduce_row(Y, m3, lane, wid + NWAVES, stats);               // consume k=1
    load_row(x0, x1, x2, wid + 3 * NWAVES, lane, i3, Y);        // row k=3
    __builtin_amdgcn_sched_barrier(0);
    reduce_row(X, m3, lane, wid + 2 * NWAVES, stats);           // consume k=2
    reduce_row(Y, m3, lane, wid + 3 * NWAVES, stats);           // consume k=3
}

// ---------------- Kernel 2a: h[b][j] = dot(stats[b,:], W1[j,:]) + b1[j] ----------------
__global__ __launch_bounds__(256) void h_kernel(const float* __restrict__ stats,
                                                const float* __restrict__ W1,
                                                const float* __restrict__ b1,
                                                float* __restrict__ hbuf) {
    const int wid  = blockIdx.x * 4 + (threadIdx.x >> 6);  // 0..8191
    const int lane = threadIdx.x & 63;
    const int j    = wid >> 4;          // 0..511
    const int b0   = (wid & 15) * 4;    // 0,4,...,60

    const float4* wr  = (const float4*)(W1 + (size_t)j * TWOC);  // 256 float4
    const float4* s0p = (const float4*)(stats + (size_t)(b0 + 0) * TWOC);
    const float4* s1p = (const float4*)(stats + (size_t)(b0 + 1) * TWOC);
    const float4* s2p = (const float4*)(stats + (size_t)(b0 + 2) * TWOC);
    const float4* s3p = (const float4*)(stats + (size_t)(b0 + 3) * TWOC);

    float a0 = 0.f, a1 = 0.f, a2 = 0.f, a3 = 0.f;
    #pragma unroll
    for (int r = 0; r < 4; ++r) {
        const int i4 = r * 64 + lane;
        const float4 wv = wr[i4];
        const float4 v0 = s0p[i4];
        const float4 v1 = s1p[i4];
        const float4 v2 = s2p[i4];
        const float4 v3 = s3p[i4];
        a0 += wv.x*v0.x + wv.y*v0.y + wv.z*v0.z + wv.w*v0.w;
        a1 += wv.x*v1.x + wv.y*v1.y + wv.z*v1.z + wv.w*v1.w;
        a2 += wv.x*v2.x + wv.y*v2.y + wv.z*v2.z + wv.w*v2.w;
        a3 += wv.x*v3.x + wv.y*v3.y + wv.z*v3.z + wv.w*v3.w;
    }
    #pragma unroll
    for (int off = 32; off; off >>= 1) {
        a0 += __shfl_down(a0, off);
        a1 += __shfl_down(a1, off);
        a2 += __shfl_down(a2, off);
        a3 += __shfl_down(a3, off);
    }
    if (lane == 0) {
        const float bb = b1[j];
        hbuf[(size_t)(b0 + 0) * NH + j] = a0 + bb;
        hbuf[(size_t)(b0 + 1) * NH + j] = a1 + bb;
        hbuf[(size_t)(b0 + 2) * NH + j] = a2 + bb;
        hbuf[(size_t)(b0 + 3) * NH + j] = a3 + bb;
    }
}

// ---------------- Kernel 2b: s[b,k,c] = dot(h[b,:], W2[k,c,:]) + b2[k,c]; w = softmax_k ----------------
__global__ __launch_bounds__(256) void sw_kernel(const float* __restrict__ hbuf,
                                                 const float* __restrict__ W2,
                                                 const float* __restrict__ b2,
                                                 float* __restrict__ wbuf) {
    const int wid  = blockIdx.x * 4 + (threadIdx.x >> 6);  // 0..8191
    const int lane = threadIdx.x & 63;
    const int c    = wid >> 4;          // 0..511
    const int b0   = (wid & 15) * 4;

    const float4* w0r = (const float4*)(W2 + ((size_t)(0 * NC + c)) * NH);  // 128 float4
    const float4* w1r = (const float4*)(W2 + ((size_t)(1 * NC + c)) * NH);
    const float4* w2r = (const float4*)(W2 + ((size_t)(2 * NC + c)) * NH);

    float acc00=0,acc01=0,acc02=0,acc03=0;
    float acc10=0,acc11=0,acc12=0,acc13=0;
    float acc20=0,acc21=0,acc22=0,acc23=0;

    #pragma unroll
    for (int r = 0; r < 2; ++r) {
        const int i4 = r * 64 + lane;
        const float4 w0v = w0r[i4];
        const float4 w1v = w1r[i4];
        const float4 w2v = w2r[i4];
        const float4 h0 = ((const float4*)(hbuf + (size_t)(b0 + 0) * NH))[i4];
        const float4 h1 = ((const float4*)(hbuf + (size_t)(b0 + 1) * NH))[i4];
        const float4 h2 = ((const float4*)(hbuf + (size_t)(b0 + 2) * NH))[i4];
        const float4 h3 = ((const float4*)(hbuf + (size_t)(b0 + 3) * NH))[i4];
        acc00 += w0v.x*h0.x + w0v.y*h0.y + w0v.z*h0.z + w0v.w*h0.w;
        acc01 += w0v.x*h1.x + w0v.y*h1.y + w0v.z*h1.z + w0v.w*h1.w;
        acc02 += w0v.x*h2.x + w0v.y*h2.y + w0v.z*h2.z + w0v.w*h2.w;
        acc03 += w0v.x*h3.x + w0v.y*h3.y + w0v.z*h3.z + w0v.w*h3.w;
        acc10 += w1v.x*h0.x + w1v.y*h0.y + w1v.z*h0.z + w1v.w*h0.w;
        acc11 += w1v.x*h1.x + w1v.y*h1.y + w1v.z*h1.z + w1v.w*h1.w;
        acc12 += w1v.x*h2.x + w1v.y*h2.y + w1v.z*h2.z + w1v.w*h2.w;
        acc13 += w1v.x*h3.x + w1v.y*h3.y + w1v.z*h3.z + w1v.w*h3.w;
        acc20 += w2v.x*h0.x + w2v.y*h0.y + w2v.z*h0.z + w2v.w*h0.w;
        acc21 += w2v.x*h1.x + w2v.y*h1.y + w2v.z*h1.z + w2v.w*h1.w;
        acc22 += w2v.x*h2.x + w2v.y*h2.y + w2v.z*h2.z + w2v.w*h2.w;
        acc23 += w2v.x*h3.x + w2v.y*h3.y + w2v.z*h3.z + w2v.w*h3.w;
    }
    #pragma unroll
    for (int off = 32; off; off >>= 1) {
        acc00 += __shfl_down(acc00, off); acc01 += __shfl_down(acc01, off);
        acc02 += __shfl_down(acc02, off); acc03 += __shfl_down(acc03, off);
        acc10 += __shfl_down(acc10, off); acc11 += __shfl_down(acc11, off);
        acc12 += __shfl_down(acc12, off); acc13 += __shfl_down(acc13, off);
        acc20 += __shfl_down(acc20, off); acc21 += __shfl_down(acc21, off);
        acc22 += __shfl_down(acc22, off); acc23 += __shfl_down(acc23, off);
    }
    if (lane == 0) {
        const float bb0 = b2[0 * NC + c];
        const float bb1 = b2[1 * NC + c];
        const float bb2 = b2[2 * NC + c];
        float v0[4] = {acc00 + bb0, acc01 + bb0, acc02 + bb0, acc03 + bb0};
        float v1[4] = {acc10 + bb1, acc11 + bb1, acc12 + bb1, acc13 + bb1};
        float v2[4] = {acc20 + bb2, acc21 + bb2, acc22 + bb2, acc23 + bb2};
        #pragma unroll
        for (int bb = 0; bb < 4; ++bb) {
            const float m  = fmaxf(v0[bb], fmaxf(v1[bb], v2[bb]));
            const float e0 = expf(v0[bb] - m);
            const float e1 = expf(v1[bb] - m);
            const float e2 = expf(v2[bb] - m);
            const float inv = 1.f / (e0 + e1 + e2);
            const size_t base = (size_t)(b0 + bb) * 3 * NC + c;
            wbuf[base + 0 * NC] = e0 * inv;
            wbuf[base + 1 * NC] = e1 * inv;
            wbuf[base + 2 * NC] = e2 * inv;
        }
    }
}

// ---------------- Kernel 3: out = w0*x0 + w1*x1 + w2*x2 ----------------
// Descending row order (boustrophedon vs stats); NT stores (out never re-read).
__global__ __launch_bounds__(256) void apply_kernel(const float* __restrict__ x0,
                                                    const float* __restrict__ x1,
                                                    const float* __restrict__ x2,
                                                    const float* __restrict__ wbuf,
                                                    float* __restrict__ out) {
    const int rblk = (int)gridDim.x - 1 - (int)blockIdx.x;     // reverse block order
    const int row  = rblk * 4 + (threadIdx.x >> 6);
    const int lane = threadIdx.x & 63;
    const int b = row >> 9;
    const int c = row & (NC - 1);

    const float4* p0 = (const float4*)x0 + (size_t)row * NT4;
    const float4* p1 = (const float4*)x1 + (size_t)row * NT4;
    const float4* p2 = (const float4*)x2 + (size_t)row * NT4;
    vfloat4*      po = (vfloat4*)out     + (size_t)row * NT4;

    const bool tail = lane < TAIL;
    const int  i3   = tail ? (192 + lane) : lane;

    const float w0 = wbuf[((size_t)b * 3 + 0) * NC + c];
    const float w1 = wbuf[((size_t)b * 3 + 1) * NC + c];
    const float w2 = wbuf[((size_t)b * 3 + 2) * NC + c];
    const float4 a0 = p0[lane];
    const float4 a1 = p0[lane + 64];
    const float4 a2 = p0[lane + 128];
    const float4 a3 = p0[i3];
    const float4 d0 = p1[lane];
    const float4 d1 = p1[lane + 64];
    const float4 d2 = p1[lane + 128];
    const float4 d3 = p1[i3];
    const float4 e0 = p2[lane];
    const float4 e1 = p2[lane + 64];
    const float4 e2 = p2[lane + 128];
    const float4 e3 = p2[i3];
    __builtin_amdgcn_sched_barrier(0);

    vfloat4 o;
    o.x = a0.x*w0 + d0.x*w1 + e0.x*w2;
    o.y = a0.y*w0 + d0.y*w1 + e0.y*w2;
    o.z = a0.z*w0 + d0.z*w1 + e0.z*w2;
    o.w = a0.w*w0 + d0.w*w1 + e0.w*w2;
    __builtin_nontemporal_store(o, &po[lane]);
    o.x = a1.x*w0 + d1.x*w1 + e1.x*w2;
    o.y = a1.y*w0 + d1.y*w1 + e1.y*w2;
    o.z = a1.z*w0 + d1.z*w1 + e1.z*w2;
    o.w = a1.w*w0 + d1.w*w1 + e1.w*w2;
    __builtin_nontemporal_store(o, &po[lane + 64]);
    o.x = a2.x*w0 + d2.x*w1 + e2.x*w2;
    o.y = a2.y*w0 + d2.y*w1 + e2.y*w2;
    o.z = a2.z*w0 + d2.z*w1 + e2.z*w2;
    o.w = a2.w*w0 + d2.w*w1 + e2.w*w2;
    __builtin_nontemporal_store(o, &po[lane + 128]);
    if (tail) {
        o.x = a3.x*w0 + d3.x*w1 + e3.x*w2;
        o.y = a3.y*w0 + d3.y*w1 + e3.y*w2;
        o.z = a3.z*w0 + d3.z*w1 + e3.z*w2;
        o.w = a3.w*w0 + d3.w*w1 + e3.w*w2;
        __builtin_nontemporal_store(o, &po[i3]);
    }
}

extern "C" void kernel_launch(void* const* d_in, const int* in_sizes, int n_in,
                              void* d_out, int out_size, void* d_ws, size_t ws_size,
                              hipStream_t stream) {
    const float* x0 = (const float*)d_in[0];
    const float* x1 = (const float*)d_in[1];
    const float* x2 = (const float*)d_in[2];
    const float* W1 = (const float*)d_in[3];
    const float* b1 = (const float*)d_in[4];
    const float* W2 = (const float*)d_in[5];
    const float* b2 = (const float*)d_in[6];
    float* out = (float*)d_out;

    float* stats = (float*)d_ws;                 // NB*TWOC floats
    float* hbuf  = stats + NB * TWOC;            // NB*NH floats
    float* wbuf  = hbuf + NB * NH;               // NB*3*NC floats

    stats_kernel<<<NWAVES / 4, 256, 0, stream>>>(x0, x1, x2, stats);
    h_kernel<<<2048, 256, 0, stream>>>(stats, W1, b1, hbuf);
    sw_kernel<<<2048, 256, 0, stream>>>(hbuf, W2, b2, wbuf);
    apply_kernel<<<NB * NC / 4, 256, 0, stream>>>(x0, x1, x2, wbuf, out);
}

// Round 8
// 169.475 us; speedup vs baseline: 1.0243x; 1.0243x over previous
//
#include <hip/hip_runtime.h>
#include <math.h>

#define NB 64
#define NC 512
#define NT 1000
#define NH 512
#define TWOC 1024
#define NT4 250   // NT/4 float4 per row
#define TAIL 58   // 250 - 192

typedef float vfloat4 __attribute__((ext_vector_type(4)));

// ---------------- Kernel 1: per-(b,c) mean/std of xs = x0+x1+x2 ----------------
// One wave per row. All 12 float4 loads batched; __launch_bounds__(256, 1)
// lifts the 64-VGPR occupancy budget that forced load->wait->consume
// serialization (28/60-VGPR compilations = 1-2 lines in flight = 3.4 TB/s wall).
__global__ __launch_bounds__(256, 1) void stats_kernel(const float* __restrict__ x0,
                                                       const float* __restrict__ x1,
                                                       const float* __restrict__ x2,
                                                       float* __restrict__ stats) {
    const int row  = blockIdx.x * 4 + (threadIdx.x >> 6);   // 0..32767 ascending
    const int lane = threadIdx.x & 63;

    const float4* p0 = (const float4*)x0 + (size_t)row * NT4;
    const float4* p1 = (const float4*)x1 + (size_t)row * NT4;
    const float4* p2 = (const float4*)x2 + (size_t)row * NT4;

    const bool tail = lane < TAIL;
    const int  i3   = tail ? (192 + lane) : lane;   // safe clamped index
    const float m3  = tail ? 1.f : 0.f;

    // issue ALL loads, unconditionally, before any consume
    const float4 a0 = p0[lane];
    const float4 a1 = p0[lane + 64];
    const float4 a2 = p0[lane + 128];
    const float4 a3 = p0[i3];
    const float4 b0 = p1[lane];
    const float4 b1 = p1[lane + 64];
    const float4 b2 = p1[lane + 128];
    const float4 b3 = p1[i3];
    const float4 c0 = p2[lane];
    const float4 c1 = p2[lane + 64];
    const float4 c2 = p2[lane + 128];
    const float4 c3 = p2[i3];
    __builtin_amdgcn_sched_barrier(0);   // nothing below may move above

    float s0 = 0.f, q0 = 0.f, s1 = 0.f, q1 = 0.f;
    float s2 = 0.f, q2 = 0.f, s3 = 0.f, q3 = 0.f;
    float v;
    v = a0.x + b0.x + c0.x; s0 += v; q0 += v * v;
    v = a0.y + b0.y + c0.y; s0 += v; q0 += v * v;
    v = a0.z + b0.z + c0.z; s0 += v; q0 += v * v;
    v = a0.w + b0.w + c0.w; s0 += v; q0 += v * v;
    v = a1.x + b1.x + c1.x; s1 += v; q1 += v * v;
    v = a1.y + b1.y + c1.y; s1 += v; q1 += v * v;
    v = a1.z + b1.z + c1.z; s1 += v; q1 += v * v;
    v = a1.w + b1.w + c1.w; s1 += v; q1 += v * v;
    v = a2.x + b2.x + c2.x; s2 += v; q2 += v * v;
    v = a2.y + b2.y + c2.y; s2 += v; q2 += v * v;
    v = a2.z + b2.z + c2.z; s2 += v; q2 += v * v;
    v = a2.w + b2.w + c2.w; s2 += v; q2 += v * v;
    v = (a3.x + b3.x + c3.x) * m3; s3 += v; q3 += v * v;
    v = (a3.y + b3.y + c3.y) * m3; s3 += v; q3 += v * v;
    v = (a3.z + b3.z + c3.z) * m3; s3 += v; q3 += v * v;
    v = (a3.w + b3.w + c3.w) * m3; s3 += v; q3 += v * v;

    float s  = (s0 + s1) + (s2 + s3);
    float sq = (q0 + q1) + (q2 + q3);

    #pragma unroll
    for (int off = 32; off; off >>= 1) {
        s  += __shfl_down(s,  off);
        sq += __shfl_down(sq, off);
    }
    if (lane == 0) {
        const float mean = s / (float)NT;
        const float var  = (sq - s * s / (float)NT) / (float)(NT - 1);
        const float sd   = sqrtf(fmaxf(var, 0.f));
        const int b = row >> 9;
        const int c = row & (NC - 1);
        stats[b * TWOC + c]      = mean;
        stats[b * TWOC + NC + c] = sd;
    }
}

// ---------------- Kernel 2a: h[b][j] = dot(stats[b,:], W1[j,:]) + b1[j] ----------------
__global__ __launch_bounds__(256) void h_kernel(const float* __restrict__ stats,
                                                const float* __restrict__ W1,
                                                const float* __restrict__ b1,
                                                float* __restrict__ hbuf) {
    const int wid  = blockIdx.x * 4 + (threadIdx.x >> 6);  // 0..8191
    const int lane = threadIdx.x & 63;
    const int j    = wid >> 4;          // 0..511
    const int b0   = (wid & 15) * 4;    // 0,4,...,60

    const float4* wr  = (const float4*)(W1 + (size_t)j * TWOC);  // 256 float4
    const float4* s0p = (const float4*)(stats + (size_t)(b0 + 0) * TWOC);
    const float4* s1p = (const float4*)(stats + (size_t)(b0 + 1) * TWOC);
    const float4* s2p = (const float4*)(stats + (size_t)(b0 + 2) * TWOC);
    const float4* s3p = (const float4*)(stats + (size_t)(b0 + 3) * TWOC);

    float a0 = 0.f, a1 = 0.f, a2 = 0.f, a3 = 0.f;
    #pragma unroll
    for (int r = 0; r < 4; ++r) {
        const int i4 = r * 64 + lane;
        const float4 wv = wr[i4];
        const float4 v0 = s0p[i4];
        const float4 v1 = s1p[i4];
        const float4 v2 = s2p[i4];
        const float4 v3 = s3p[i4];
        a0 += wv.x*v0.x + wv.y*v0.y + wv.z*v0.z + wv.w*v0.w;
        a1 += wv.x*v1.x + wv.y*v1.y + wv.z*v1.z + wv.w*v1.w;
        a2 += wv.x*v2.x + wv.y*v2.y + wv.z*v2.z + wv.w*v2.w;
        a3 += wv.x*v3.x + wv.y*v3.y + wv.z*v3.z + wv.w*v3.w;
    }
    #pragma unroll
    for (int off = 32; off; off >>= 1) {
        a0 += __shfl_down(a0, off);
        a1 += __shfl_down(a1, off);
        a2 += __shfl_down(a2, off);
        a3 += __shfl_down(a3, off);
    }
    if (lane == 0) {
        const float bb = b1[j];
        hbuf[(size_t)(b0 + 0) * NH + j] = a0 + bb;
        hbuf[(size_t)(b0 + 1) * NH + j] = a1 + bb;
        hbuf[(size_t)(b0 + 2) * NH + j] = a2 + bb;
        hbuf[(size_t)(b0 + 3) * NH + j] = a3 + bb;
    }
}

// ---------------- Kernel 2b: s[b,k,c] = dot(h[b,:], W2[k,c,:]) + b2[k,c]; w = softmax_k ----------------
__global__ __launch_bounds__(256) void sw_kernel(const float* __restrict__ hbuf,
                                                 const float* __restrict__ W2,
                                                 const float* __restrict__ b2,
                                                 float* __restrict__ wbuf) {
    const int wid  = blockIdx.x * 4 + (threadIdx.x >> 6);  // 0..8191
    const int lane = threadIdx.x & 63;
    const int c    = wid >> 4;          // 0..511
    const int b0   = (wid & 15) * 4;

    const float4* w0r = (const float4*)(W2 + ((size_t)(0 * NC + c)) * NH);  // 128 float4
    const float4* w1r = (const float4*)(W2 + ((size_t)(1 * NC + c)) * NH);
    const float4* w2r = (const float4*)(W2 + ((size_t)(2 * NC + c)) * NH);

    float acc00=0,acc01=0,acc02=0,acc03=0;
    float acc10=0,acc11=0,acc12=0,acc13=0;
    float acc20=0,acc21=0,acc22=0,acc23=0;

    #pragma unroll
    for (int r = 0; r < 2; ++r) {
        const int i4 = r * 64 + lane;
        const float4 w0v = w0r[i4];
        const float4 w1v = w1r[i4];
        const float4 w2v = w2r[i4];
        const float4 h0 = ((const float4*)(hbuf + (size_t)(b0 + 0) * NH))[i4];
        const float4 h1 = ((const float4*)(hbuf + (size_t)(b0 + 1) * NH))[i4];
        const float4 h2 = ((const float4*)(hbuf + (size_t)(b0 + 2) * NH))[i4];
        const float4 h3 = ((const float4*)(hbuf + (size_t)(b0 + 3) * NH))[i4];
        acc00 += w0v.x*h0.x + w0v.y*h0.y + w0v.z*h0.z + w0v.w*h0.w;
        acc01 += w0v.x*h1.x + w0v.y*h1.y + w0v.z*h1.z + w0v.w*h1.w;
        acc02 += w0v.x*h2.x + w0v.y*h2.y + w0v.z*h2.z + w0v.w*h2.w;
        acc03 += w0v.x*h3.x + w0v.y*h3.y + w0v.z*h3.z + w0v.w*h3.w;
        acc10 += w1v.x*h0.x + w1v.y*h0.y + w1v.z*h0.z + w1v.w*h0.w;
        acc11 += w1v.x*h1.x + w1v.y*h1.y + w1v.z*h1.z + w1v.w*h1.w;
        acc12 += w1v.x*h2.x + w1v.y*h2.y + w1v.z*h2.z + w1v.w*h2.w;
        acc13 += w1v.x*h3.x + w1v.y*h3.y + w1v.z*h3.z + w1v.w*h3.w;
        acc20 += w2v.x*h0.x + w2v.y*h0.y + w2v.z*h0.z + w2v.w*h0.w;
        acc21 += w2v.x*h1.x + w2v.y*h1.y + w2v.z*h1.z + w2v.w*h1.w;
        acc22 += w2v.x*h2.x + w2v.y*h2.y + w2v.z*h2.z + w2v.w*h2.w;
        acc23 += w2v.x*h3.x + w2v.y*h3.y + w2v.z*h3.z + w2v.w*h3.w;
    }
    #pragma unroll
    for (int off = 32; off; off >>= 1) {
        acc00 += __shfl_down(acc00, off); acc01 += __shfl_down(acc01, off);
        acc02 += __shfl_down(acc02, off); acc03 += __shfl_down(acc03, off);
        acc10 += __shfl_down(acc10, off); acc11 += __shfl_down(acc11, off);
        acc12 += __shfl_down(acc12, off); acc13 += __shfl_down(acc13, off);
        acc20 += __shfl_down(acc20, off); acc21 += __shfl_down(acc21, off);
        acc22 += __shfl_down(acc22, off); acc23 += __shfl_down(acc23, off);
    }
    if (lane == 0) {
        const float bb0 = b2[0 * NC + c];
        const float bb1 = b2[1 * NC + c];
        const float bb2 = b2[2 * NC + c];
        float v0[4] = {acc00 + bb0, acc01 + bb0, acc02 + bb0, acc03 + bb0};
        float v1[4] = {acc10 + bb1, acc11 + bb1, acc12 + bb1, acc13 + bb1};
        float v2[4] = {acc20 + bb2, acc21 + bb2, acc22 + bb2, acc23 + bb2};
        #pragma unroll
        for (int bb = 0; bb < 4; ++bb) {
            const float m  = fmaxf(v0[bb], fmaxf(v1[bb], v2[bb]));
            const float e0 = expf(v0[bb] - m);
            const float e1 = expf(v1[bb] - m);
            const float e2 = expf(v2[bb] - m);
            const float inv = 1.f / (e0 + e1 + e2);
            const size_t base = (size_t)(b0 + bb) * 3 * NC + c;
            wbuf[base + 0 * NC] = e0 * inv;
            wbuf[base + 1 * NC] = e1 * inv;
            wbuf[base + 2 * NC] = e2 * inv;
        }
    }
}

// ---------------- Kernel 3: out = w0*x0 + w1*x1 + w2*x2 ----------------
// Descending row order (boustrophedon vs stats); NT stores (out never re-read).
__global__ __launch_bounds__(256) void apply_kernel(const float* __restrict__ x0,
                                                    const float* __restrict__ x1,
                                                    const float* __restrict__ x2,
                                                    const float* __restrict__ wbuf,
                                                    float* __restrict__ out) {
    const int rblk = (int)gridDim.x - 1 - (int)blockIdx.x;     // reverse block order
    const int row  = rblk * 4 + (threadIdx.x >> 6);
    const int lane = threadIdx.x & 63;
    const int b = row >> 9;
    const int c = row & (NC - 1);

    const float4* p0 = (const float4*)x0 + (size_t)row * NT4;
    const float4* p1 = (const float4*)x1 + (size_t)row * NT4;
    const float4* p2 = (const float4*)x2 + (size_t)row * NT4;
    vfloat4*      po = (vfloat4*)out     + (size_t)row * NT4;

    const bool tail = lane < TAIL;
    const int  i3   = tail ? (192 + lane) : lane;

    const float w0 = wbuf[((size_t)b * 3 + 0) * NC + c];
    const float w1 = wbuf[((size_t)b * 3 + 1) * NC + c];
    const float w2 = wbuf[((size_t)b * 3 + 2) * NC + c];
    const float4 a0 = p0[lane];
    const float4 a1 = p0[lane + 64];
    const float4 a2 = p0[lane + 128];
    const float4 a3 = p0[i3];
    const float4 d0 = p1[lane];
    const float4 d1 = p1[lane + 64];
    const float4 d2 = p1[lane + 128];
    const float4 d3 = p1[i3];
    const float4 e0 = p2[lane];
    const float4 e1 = p2[lane + 64];
    const float4 e2 = p2[lane + 128];
    const float4 e3 = p2[i3];
    __builtin_amdgcn_sched_barrier(0);

    vfloat4 o;
    o.x = a0.x*w0 + d0.x*w1 + e0.x*w2;
    o.y = a0.y*w0 + d0.y*w1 + e0.y*w2;
    o.z = a0.z*w0 + d0.z*w1 + e0.z*w2;
    o.w = a0.w*w0 + d0.w*w1 + e0.w*w2;
    __builtin_nontemporal_store(o, &po[lane]);
    o.x = a1.x*w0 + d1.x*w1 + e1.x*w2;
    o.y = a1.y*w0 + d1.y*w1 + e1.y*w2;
    o.z = a1.z*w0 + d1.z*w1 + e1.z*w2;
    o.w = a1.w*w0 + d1.w*w1 + e1.w*w2;
    __builtin_nontemporal_store(o, &po[lane + 64]);
    o.x = a2.x*w0 + d2.x*w1 + e2.x*w2;
    o.y = a2.y*w0 + d2.y*w1 + e2.y*w2;
    o.z = a2.z*w0 + d2.z*w1 + e2.z*w2;
    o.w = a2.w*w0 + d2.w*w1 + e2.w*w2;
    __builtin_nontemporal_store(o, &po[lane + 128]);
    if (tail) {
        o.x = a3.x*w0 + d3.x*w1 + e3.x*w2;
        o.y = a3.y*w0 + d3.y*w1 + e3.y*w2;
        o.z = a3.z*w0 + d3.z*w1 + e3.z*w2;
        o.w = a3.w*w0 + d3.w*w1 + e3.w*w2;
        __builtin_nontemporal_store(o, &po[i3]);
    }
}

extern "C" void kernel_launch(void* const* d_in, const int* in_sizes, int n_in,
                              void* d_out, int out_size, void* d_ws, size_t ws_size,
                              hipStream_t stream) {
    const float* x0 = (const float*)d_in[0];
    const float* x1 = (const float*)d_in[1];
    const float* x2 = (const float*)d_in[2];
    const float* W1 = (const float*)d_in[3];
    const float* b1 = (const float*)d_in[4];
    const float* W2 = (const float*)d_in[5];
    const float* b2 = (const float*)d_in[6];
    float* out = (float*)d_out;

    float* stats = (float*)d_ws;                 // NB*TWOC floats
    float* hbuf  = stats + NB * TWOC;            // NB*NH floats
    float* wbuf  = hbuf + NB * NH;               // NB*3*NC floats

    stats_kernel<<<NB * NC / 4, 256, 0, stream>>>(x0, x1, x2, stats);
    h_kernel<<<2048, 256, 0, stream>>>(stats, W1, b1, hbuf);
    sw_kernel<<<2048, 256, 0, stream>>>(hbuf, W2, b2, wbuf);
    apply_kernel<<<NB * NC / 4, 256, 0, stream>>>(x0, x1, x2, wbuf, out);
}